// Round 5
// baseline (611.649 us; speedup 1.0000x reference)
//
#include <hip/hip_runtime.h>
#include <cstdint>
#include <cstddef>

typedef __attribute__((ext_vector_type(8))) short bf16x8;
typedef __attribute__((ext_vector_type(4))) float f32x4;

// LDS geometry for gemm1 A-tiles (fragment-ordered split-bf16)
#define ROWSTR 40              // shorts per row (32 data + 8 pad) -> 80 B, 16B-aligned rows
#define PLANE  (64 * ROWSTR)   // shorts per k-chunk plane
#define ABUF   (4 * PLANE)     // shorts per buffer (4 k-chunks)

// ---------------- bf16 split helpers ----------------

__device__ __forceinline__ unsigned bf_rne(float x) {
  unsigned u = __float_as_uint(x);
  return (u + 0x7FFFu + ((u >> 16) & 1u)) >> 16;
}

__device__ __forceinline__ void split1(float x, short& hi, short& lo) {
  unsigned hb = bf_rne(x);
  hi = (short)hb;
  float fh = __uint_as_float(hb << 16);
  lo = (short)bf_rne(x - fh);
}

__device__ __forceinline__ void split8(const float4& p, const float4& q, bf16x8& h, bf16x8& l) {
  short hh, ll;
  split1(p.x, hh, ll); h[0] = hh; l[0] = ll;
  split1(p.y, hh, ll); h[1] = hh; l[1] = ll;
  split1(p.z, hh, ll); h[2] = hh; l[2] = ll;
  split1(p.w, hh, ll); h[3] = hh; l[3] = ll;
  split1(q.x, hh, ll); h[4] = hh; l[4] = ll;
  split1(q.y, hh, ll); h[5] = hh; l[5] = ll;
  split1(q.z, hh, ll); h[6] = hh; l[6] = ll;
  split1(q.w, hh, ll); h[7] = hh; l[7] = ll;
}

// ---------------- prep: fragment-ordered split-bf16 weights ----------------

__global__ void prep1_kernel(const float* __restrict__ pw, const float* __restrict__ pb,
                             const float* __restrict__ w1,
                             short* __restrict__ Bh, short* __restrict__ Bl,
                             float* __restrict__ biasf) {
  int idx = blockIdx.x * 256 + threadIdx.x;
  if (idx < 896 * 64) {
    int gk = idx >> 6, col = idx & 63;
    float val;
    if (gk < 768) {
      float acc = 0.0f;
      #pragma unroll 8
      for (int m = 0; m < 32; ++m) acc = fmaf(pw[gk * 32 + m], w1[(80 + m) * 64 + col], acc);
      val = acc;
    } else if (gk < 832) val = w1[(gk - 768) * 64 + col];
    else if (gk < 848)   val = w1[(64 + gk - 832) * 64 + col];
    else if (gk < 864)   val = w1[(112 + gk - 848) * 64 + col];
    else if (gk < 880)   val = w1[(128 + gk - 864) * 64 + col];
    else                 val = 0.0f;
    int chunk = gk >> 5, k = gk & 31;
    int g, j;
    if (k < 16) { g = k >> 2; j = k & 3; } else { int k2 = k - 16; g = k2 >> 2; j = 4 + (k2 & 3); }
    size_t o = ((size_t)(chunk * 4 + g) * 64 + col) * 8 + j;
    short hh, ll; split1(val, hh, ll);
    Bh[o] = hh; Bl[o] = ll;
  } else if (idx < 896 * 64 + 64) {
    int col = idx - 896 * 64;
    float acc = 0.0f;
    for (int m = 0; m < 32; ++m) acc = fmaf(pb[m], w1[(80 + m) * 64 + col], acc);
    biasf[col] = acc;
  }
}

__global__ void prep2_kernel(const float* __restrict__ w2,
                             short* __restrict__ B2h, short* __restrict__ B2l) {
  int idx = blockIdx.x * 256 + threadIdx.x;
  if (idx >= 64 * 64) return;
  int gk = idx >> 6, col = idx & 63;
  float val = w2[gk * 64 + col];
  int chunk = gk >> 5, k = gk & 31;
  int g, j;
  if (k < 16) { g = k >> 2; j = k & 3; } else { int k2 = k - 16; g = k2 >> 2; j = 4 + (k2 & 3); }
  size_t o = ((size_t)(chunk * 4 + g) * 64 + col) * 8 + j;
  short hh, ll; split1(val, hh, ll);
  B2h[o] = hh; B2l[o] = ll;
}

// ---------------- CSR build (deg folded into cnt pass) ----------------

__global__ void init_kernel(float* __restrict__ deg, int* __restrict__ cnt, int n) {
  int i = blockIdx.x * 256 + threadIdx.x;
  if (i < n) { deg[i] = 1.0f; cnt[i] = 0; }   // 1.0 = self-loop weight
}

__global__ void cnt_kernel(const int* __restrict__ ei, const float* __restrict__ ew,
                           int* __restrict__ cnt, float* __restrict__ deg, int E) {
  int e = blockIdx.x * 256 + threadIdx.x;
  if (e >= E) return;
  int col = ei[E + e];
  atomicAdd(&cnt[col], 1);
  atomicAdd(&deg[col], ew[e]);
}

__global__ void dinv_kernel(float* __restrict__ deg, int n) {
  int i = blockIdx.x * 256 + threadIdx.x;
  if (i < n) deg[i] = rsqrtf(deg[i]);   // deg >= 1 always (self-loop)
}

__global__ __launch_bounds__(256) void scan_blk(const int* __restrict__ cnt,
                                                int* __restrict__ colp,
                                                int* __restrict__ bsum, int n) {
  __shared__ int ws[4];
  int t = threadIdx.x, lane = t & 63, w = t >> 6;
  int i = blockIdx.x * 256 + t;
  int v = (i < n) ? cnt[i] : 0;
  int x = v;
  #pragma unroll
  for (int off = 1; off < 64; off <<= 1) { int y = __shfl_up(x, off); if (lane >= off) x += y; }
  if (lane == 63) ws[w] = x;
  __syncthreads();
  if (t == 0) {
    int s = 0;
    #pragma unroll
    for (int k = 0; k < 4; ++k) { int tmp = ws[k]; ws[k] = s; s += tmp; }
    bsum[blockIdx.x] = s;
  }
  __syncthreads();
  if (i < n) colp[i] = ws[w] + x - v;
}

__global__ __launch_bounds__(512) void scan_top(int* __restrict__ bsum,
                                                int* __restrict__ colp, int nb, int n) {
  __shared__ int ws[8];
  int t = threadIdx.x, lane = t & 63, w = t >> 6;
  int v = (t < nb) ? bsum[t] : 0;
  int x = v;
  #pragma unroll
  for (int off = 1; off < 64; off <<= 1) { int y = __shfl_up(x, off); if (lane >= off) x += y; }
  if (lane == 63) ws[w] = x;
  __syncthreads();
  if (t == 0) {
    int s = 0;
    #pragma unroll
    for (int k = 0; k < 8; ++k) { int tmp = ws[k]; ws[k] = s; s += tmp; }
  }
  __syncthreads();
  int excl = ws[w] + x - v;
  if (t < nb) bsum[t] = excl;
  if (t == nb - 1) colp[n] = excl + v;
}

__global__ void scan_add(int* __restrict__ colp, int* __restrict__ fillp,
                         const int* __restrict__ bsum, int n) {
  int i = blockIdx.x * 256 + threadIdx.x;
  if (i < n) {
    int c = colp[i] + bsum[blockIdx.x];
    colp[i] = c;
    fillp[i] = c;
  }
}

__global__ void fill_kernel(const int* __restrict__ ei, const float* __restrict__ ew,
                            const float* __restrict__ dinv, int* __restrict__ fillp,
                            int2* __restrict__ csr, int E) {
  int e = blockIdx.x * 256 + threadIdx.x;
  if (e >= E) return;
  int row = ei[e], col = ei[E + e];
  int pos = atomicAdd(&fillp[col], 1);
  csr[pos] = make_int2(row, __float_as_int(ew[e] * dinv[row]));
}

// ---------------- gemm1: LDS-staged, contiguous-DRAM, double-buffered ----------------
// Block owns 64 consecutive rows (192 KB contiguous llm). 6 iterations stage a
// 64x128 f32 panel -> split-bf16 fragment-ordered LDS (XOR bank swizzle by kc).
// 4 waves: wave wv computes row-tile wv (16 rows) x all 64 cols.

__device__ __forceinline__ void loadB(const short* __restrict__ Bh, const short* __restrict__ Bl,
                                      int c, int g, int r16, bf16x8 (&bh)[4], bf16x8 (&bl)[4]) {
  #pragma unroll
  for (int ct = 0; ct < 4; ++ct) {
    size_t o = ((size_t)(c * 4 + g) * 64 + ct * 16 + r16) * 8;
    bh[ct] = *(const bf16x8*)(Bh + o);
    bl[ct] = *(const bf16x8*)(Bl + o);
  }
}

__device__ __forceinline__ void mfma12(f32x4 (&acc)[4], const bf16x8& ah, const bf16x8& al,
                                       const bf16x8 (&bh)[4], const bf16x8 (&bl)[4]) {
  #pragma unroll
  for (int ct = 0; ct < 4; ++ct) {
    acc[ct] = __builtin_amdgcn_mfma_f32_16x16x32_bf16(ah, bh[ct], acc[ct], 0, 0, 0);
    acc[ct] = __builtin_amdgcn_mfma_f32_16x16x32_bf16(ah, bl[ct], acc[ct], 0, 0, 0);
    acc[ct] = __builtin_amdgcn_mfma_f32_16x16x32_bf16(al, bh[ct], acc[ct], 0, 0, 0);
  }
}

__global__ __launch_bounds__(256, 2) void gemm1_kernel(
    const float* __restrict__ llm, const short* __restrict__ Bh, const short* __restrict__ Bl,
    const int* __restrict__ names, const int* __restrict__ types,
    const float* __restrict__ beh, const float* __restrict__ nemb,
    const float* __restrict__ temb, const float* __restrict__ biasf,
    float* __restrict__ out, int n)
{
  __shared__ short Ah[2][ABUF];
  __shared__ short Al[2][ABUF];

  // bijective XCD swizzle
  int nwg = gridDim.x;
  int b = blockIdx.x;
  int q = nwg >> 3, r = nwg & 7;
  int xcd = b & 7, bidx = b >> 3;
  int swz = (xcd < r ? xcd * (q + 1) : r * (q + 1) + (xcd - r) * q) + bidx;

  const int tid = threadIdx.x;
  const int lane = tid & 63, wv = tid >> 6;
  const int g = lane >> 4, r16 = lane & 15;
  const int base = swz * 64;

  // staging ids: thread covers (row = rw8 + it*8, float4 colq) of a 64x128 panel
  const int colq = tid & 31;
  const int rw8  = tid >> 5;
  const int kc_s = colq >> 3;
  const int qq   = colq & 7;
  const int pos0 = (((qq & 3) * 8) + ((qq >> 2) * 4)) ^ (kc_s << 3);  // frag pos, bank-swizzled
  const int wbase = kc_s * PLANE + rw8 * ROWSTR + pos0;

  // per-thread staging row pointers (8 rows, 8 apart), clamped
  const float* rp[8];
  #pragma unroll
  for (int it = 0; it < 8; ++it) {
    int grow = base + rw8 + it * 8;
    if (grow > n - 1) grow = n - 1;
    rp[it] = llm + (size_t)grow * 768 + colq * 4;
  }

  // compute-side ids
  const int arowL = wv * 16 + r16;        // LDS row this lane reads
  int arowG = base + arowL;
  if (arowG > n - 1) arowG = n - 1;
  const int nm = names[arowG], tp = types[arowG];

  f32x4 acc[4];
  #pragma unroll
  for (int ct = 0; ct < 4; ++ct) { acc[ct][0] = 0.f; acc[ct][1] = 0.f; acc[ct][2] = 0.f; acc[ct][3] = 0.f; }

  float4 sv[8];
  // prologue: stage panel 0 into buffer 0
  #pragma unroll
  for (int it = 0; it < 8; ++it) sv[it] = *(const float4*)(rp[it]);
  #pragma unroll
  for (int it = 0; it < 8; ++it) {
    short4 h4, l4;
    split1(sv[it].x, h4.x, l4.x); split1(sv[it].y, h4.y, l4.y);
    split1(sv[it].z, h4.z, l4.z); split1(sv[it].w, h4.w, l4.w);
    *(short4*)&Ah[0][wbase + it * 8 * ROWSTR] = h4;
    *(short4*)&Al[0][wbase + it * 8 * ROWSTR] = l4;
  }
  __syncthreads();

  int cur = 0;
  #pragma unroll 1
  for (int i = 0; i < 6; ++i) {
    if (i < 5) {
      #pragma unroll
      for (int it = 0; it < 8; ++it) sv[it] = *(const float4*)(rp[it] + (i + 1) * 128);
    }
    __builtin_amdgcn_sched_barrier(0);   // pin prefetch issue above compute
    #pragma unroll
    for (int kc = 0; kc < 4; ++kc) {
      bf16x8 bh[4], bl[4];
      loadB(Bh, Bl, i * 4 + kc, g, r16, bh, bl);
      int ro = kc * PLANE + arowL * ROWSTR + ((g ^ kc) * 8);
      bf16x8 ah = *(const bf16x8*)&Ah[cur][ro];
      bf16x8 al = *(const bf16x8*)&Al[cur][ro];
      mfma12(acc, ah, al, bh, bl);
    }
    if (i < 5) {
      #pragma unroll
      for (int it = 0; it < 8; ++it) {
        short4 h4, l4;
        split1(sv[it].x, h4.x, l4.x); split1(sv[it].y, h4.y, l4.y);
        split1(sv[it].z, h4.z, l4.z); split1(sv[it].w, h4.w, l4.w);
        *(short4*)&Ah[cur ^ 1][wbase + it * 8 * ROWSTR] = h4;
        *(short4*)&Al[cur ^ 1][wbase + it * 8 * ROWSTR] = l4;
      }
    }
    __syncthreads();
    cur ^= 1;
  }

  // ---- tail: chunks 24/25 = name_emb, 26 = type|behav[0:16], 27 = behav[16:32]|0 ----
  bf16x8 bh[4], bl[4], ah, al;
  const float* pN = nemb + (size_t)nm * 64 + g * 4;
  #pragma unroll
  for (int t = 0; t < 2; ++t) {
    float4 l = *(const float4*)(pN + t * 32), h = *(const float4*)(pN + t * 32 + 16);
    loadB(Bh, Bl, 24 + t, g, r16, bh, bl);
    split8(l, h, ah, al);
    mfma12(acc, ah, al, bh, bl);
  }
  {
    float4 l = *(const float4*)(temb + (size_t)tp * 16 + g * 4);
    float4 h = *(const float4*)(beh + (size_t)arowG * 32 + g * 4);
    loadB(Bh, Bl, 26, g, r16, bh, bl);
    split8(l, h, ah, al);
    mfma12(acc, ah, al, bh, bl);
  }
  {
    const float4 z = make_float4(0.f, 0.f, 0.f, 0.f);
    float4 l = *(const float4*)(beh + (size_t)arowG * 32 + 16 + g * 4);
    loadB(Bh, Bl, 27, g, r16, bh, bl);
    split8(l, z, ah, al);
    mfma12(acc, ah, al, bh, bl);
  }

  // C/D: col = lane&15 (+16*ct), row = g*4 + reg, tile base = base + wv*16
  #pragma unroll
  for (int ct = 0; ct < 4; ++ct) {
    int col = ct * 16 + r16;
    float bf = biasf[col];
    #pragma unroll
    for (int rr = 0; rr < 4; ++rr) {
      int node = base + wv * 16 + g * 4 + rr;
      if (node < n) out[(size_t)node * 64 + col] = acc[ct][rr] + bf;
    }
  }
}

// ---------------- gemm2: h @ W2, streaming (rows contiguous -> dense 4KB regions) ----------------

__device__ __forceinline__ void mfma24(f32x4 (&acc)[2][4],
                                       const bf16x8& ah0, const bf16x8& al0,
                                       const bf16x8& ah1, const bf16x8& al1,
                                       const bf16x8 (&bh)[4], const bf16x8 (&bl)[4]) {
  #pragma unroll
  for (int ct = 0; ct < 4; ++ct) {
    acc[0][ct] = __builtin_amdgcn_mfma_f32_16x16x32_bf16(ah0, bh[ct], acc[0][ct], 0, 0, 0);
    acc[0][ct] = __builtin_amdgcn_mfma_f32_16x16x32_bf16(ah0, bl[ct], acc[0][ct], 0, 0, 0);
    acc[0][ct] = __builtin_amdgcn_mfma_f32_16x16x32_bf16(al0, bh[ct], acc[0][ct], 0, 0, 0);
  }
  #pragma unroll
  for (int ct = 0; ct < 4; ++ct) {
    acc[1][ct] = __builtin_amdgcn_mfma_f32_16x16x32_bf16(ah1, bh[ct], acc[1][ct], 0, 0, 0);
    acc[1][ct] = __builtin_amdgcn_mfma_f32_16x16x32_bf16(ah1, bl[ct], acc[1][ct], 0, 0, 0);
    acc[1][ct] = __builtin_amdgcn_mfma_f32_16x16x32_bf16(al1, bh[ct], acc[1][ct], 0, 0, 0);
  }
}

__global__ __launch_bounds__(256, 4) void gemm2_kernel(
    const float* __restrict__ h, const short* __restrict__ B2h, const short* __restrict__ B2l,
    float* __restrict__ out, int n)
{
  int w = blockIdx.x * 4 + (threadIdx.x >> 6);
  int nw = (n + 31) >> 5;
  if (w >= nw) return;
  int lane = threadIdx.x & 63;
  int g = lane >> 4, r16 = lane & 15;
  int base = w * 32;
  int arow0 = base + r16;      if (arow0 > n - 1) arow0 = n - 1;
  int arow1 = base + 16 + r16; if (arow1 > n - 1) arow1 = n - 1;

  f32x4 acc[2][4];
  #pragma unroll
  for (int i = 0; i < 2; ++i)
    #pragma unroll
    for (int j = 0; j < 4; ++j) { acc[i][j][0] = 0.f; acc[i][j][1] = 0.f; acc[i][j][2] = 0.f; acc[i][j][3] = 0.f; }

  #pragma unroll
  for (int c = 0; c < 2; ++c) {
    bf16x8 bh[4], bl[4];
    loadB(B2h, B2l, c, g, r16, bh, bl);
    const float* p0 = h + (size_t)arow0 * 64 + c * 32 + g * 4;
    const float* p1 = h + (size_t)arow1 * 64 + c * 32 + g * 4;
    float4 lo0 = *(const float4*)p0, hi0 = *(const float4*)(p0 + 16);
    float4 lo1 = *(const float4*)p1, hi1 = *(const float4*)(p1 + 16);
    bf16x8 ah0, al0, ah1, al1;
    split8(lo0, hi0, ah0, al0);
    split8(lo1, hi1, ah1, al1);
    mfma24(acc, ah0, al0, ah1, al1, bh, bl);
  }

  #pragma unroll
  for (int ct = 0; ct < 4; ++ct) {
    int col = ct * 16 + r16;
    #pragma unroll
    for (int rr = 0; rr < 4; ++rr) {
      int node0 = base + g * 4 + rr;
      if (node0 < n) out[(size_t)node0 * 64 + col] = acc[0][ct][rr];
      int node1 = base + 16 + g * 4 + rr;
      if (node1 < n) out[(size_t)node1 * 64 + col] = acc[1][ct][rr];
    }
  }
}

// ---------------- aggregation ----------------

__global__ __launch_bounds__(256) void agg_kernel(
    const float* __restrict__ h, const int* __restrict__ colp,
    const int2* __restrict__ csr, const float* __restrict__ dinv,
    const float* __restrict__ bias, float* __restrict__ out, int n)
{
  int wid = threadIdx.x >> 6, lane = threadIdx.x & 63;
  int j = blockIdx.x * 4 + wid;
  if (j >= n) return;
  float dj = dinv[j];
  float hj = h[(size_t)j * 64 + lane];
  int e0 = colp[j], e1 = colp[j + 1];
  float s = 0.0f;
  int e = e0;
  for (; e + 4 <= e1; e += 4) {
    int2 m0 = csr[e], m1 = csr[e + 1], m2 = csr[e + 2], m3 = csr[e + 3];
    float f0 = h[(size_t)m0.x * 64 + lane];
    float f1 = h[(size_t)m1.x * 64 + lane];
    float f2 = h[(size_t)m2.x * 64 + lane];
    float f3 = h[(size_t)m3.x * 64 + lane];
    s = fmaf(__int_as_float(m0.y), f0, s);
    s = fmaf(__int_as_float(m1.y), f1, s);
    s = fmaf(__int_as_float(m2.y), f2, s);
    s = fmaf(__int_as_float(m3.y), f3, s);
  }
  for (; e < e1; ++e) {
    int2 m = csr[e];
    s = fmaf(__int_as_float(m.y), h[(size_t)m.x * 64 + lane], s);
  }
  float acc = bias[lane] + dj * fmaf(dj, hj, s);
  out[(size_t)j * 64 + lane] = fmaxf(acc, 0.0f);
}

// ---------------- pool + classifier ----------------

__global__ __launch_bounds__(256) void pool_kernel(const float* __restrict__ x,
                                                   const int* __restrict__ batch,
                                                   float* __restrict__ pooled, int n) {
  __shared__ float red[4][64];
  __shared__ int range_s[2];
  int gph = blockIdx.x;
  int tid = threadIdx.x, wid = tid >> 6, lane = tid & 63;
  if (tid < 2) {
    int target = gph + tid;
    int lo = 0, hi = n;
    while (lo < hi) { int m = (lo + hi) >> 1; if (batch[m] < target) lo = m + 1; else hi = m; }
    range_s[tid] = lo;
  }
  __syncthreads();
  int lo = range_s[0], hi = range_s[1];
  float acc = 0.0f;
  for (int i = lo + wid; i < hi; i += 4) acc += x[(size_t)i * 64 + lane];
  red[wid][lane] = acc;
  __syncthreads();
  if (tid < 64) {
    float sum = red[0][lane] + red[1][lane] + red[2][lane] + red[3][lane];
    float cntf = (float)(hi - lo);
    pooled[gph * 64 + lane] = sum / fmaxf(cntf, 1.0f);
  }
}

__global__ void cls_kernel(const float* __restrict__ pooled, const float* __restrict__ cw,
                           const float* __restrict__ cb, float* __restrict__ out) {
  int t = threadIdx.x;
  int gph = t >> 1, c = t & 1;
  float acc = cb[c];
  #pragma unroll 8
  for (int k = 0; k < 64; ++k) acc = fmaf(pooled[gph * 64 + k], cw[k * 2 + c], acc);
  out[gph * 2 + c] = acc;
}

// ---------------- launch ----------------

extern "C" void kernel_launch(void* const* d_in, const int* in_sizes, int n_in,
                              void* d_out, int out_size, void* d_ws, size_t ws_size,
                              hipStream_t stream) {
  const int*   x_names  = (const int*)  d_in[0];
  const int*   x_types  = (const int*)  d_in[1];
  const float* behav    = (const float*)d_in[2];
  const int*   ei       = (const int*)  d_in[3];
  const float* ew       = (const float*)d_in[4];
  const int*   batch    = (const int*)  d_in[5];
  const float* llm      = (const float*)d_in[6];
  const float* name_emb = (const float*)d_in[7];
  const float* type_emb = (const float*)d_in[8];
  const float* pw       = (const float*)d_in[9];
  const float* pb       = (const float*)d_in[10];
  const float* w1       = (const float*)d_in[11];
  const float* b1       = (const float*)d_in[12];
  const float* w2       = (const float*)d_in[13];
  const float* b2       = (const float*)d_in[14];
  const float* cw       = (const float*)d_in[15];
  const float* cb       = (const float*)d_in[16];

  const int N = in_sizes[0];
  const int E = in_sizes[4];
  const int nb = (N + 255) / 256;
  const int eb = (E + 255) / 256;
  const int g1blocks = (N + 63) / 64;
  const int g2blocks = ((N + 31) / 32 + 3) / 4;

  char* p = (char*)d_ws;
  auto alloc = [&](size_t bytes) -> void* {
    void* r = (void*)p; p += (bytes + 255) & ~(size_t)255; return r;
  };
  float* dinv   = (float*)alloc((size_t)N * 4);
  int*   cnt    = (int*)  alloc((size_t)N * 4);
  int*   colp   = (int*)  alloc((size_t)(N + 1) * 4);
  int*   fillp  = (int*)  alloc((size_t)N * 4);
  int2*  csr    = (int2*) alloc((size_t)E * 8);
  int*   bsum   = (int*)  alloc((size_t)(nb + 1) * 4);
  short* Bh     = (short*)alloc((size_t)896 * 64 * 2);
  short* Bl     = (short*)alloc((size_t)896 * 64 * 2);
  short* B2h    = (short*)alloc((size_t)64 * 64 * 2);
  short* B2l    = (short*)alloc((size_t)64 * 64 * 2);
  float* biasf  = (float*)alloc((size_t)64 * 4);
  float* bufX   = (float*)alloc((size_t)N * 64 * 4);
  float* bufY   = (float*)alloc((size_t)N * 64 * 4);
  float* pooled = (float*)alloc((size_t)128 * 64 * 4);
  (void)ws_size; (void)n_in; (void)out_size;

  init_kernel<<<nb, 256, 0, stream>>>(dinv, cnt, N);
  prep1_kernel<<<(896 * 64 + 64 + 255) / 256, 256, 0, stream>>>(pw, pb, w1, Bh, Bl, biasf);
  prep2_kernel<<<16, 256, 0, stream>>>(w2, B2h, B2l);
  cnt_kernel<<<eb, 256, 0, stream>>>(ei, ew, cnt, dinv, E);
  dinv_kernel<<<nb, 256, 0, stream>>>(dinv, N);
  scan_blk<<<nb, 256, 0, stream>>>(cnt, colp, bsum, N);
  scan_top<<<1, 512, 0, stream>>>(bsum, colp, nb, N);
  scan_add<<<nb, 256, 0, stream>>>(colp, fillp, bsum, N);
  fill_kernel<<<eb, 256, 0, stream>>>(ei, ew, dinv, fillp, csr, E);

  gemm1_kernel<<<g1blocks, 256, 0, stream>>>(llm, Bh, Bl, x_names, x_types, behav,
                                             name_emb, type_emb, biasf, bufX, N);
  agg_kernel<<<(N + 3) / 4, 256, 0, stream>>>(bufX, colp, csr, dinv, b1, bufY, N);
  gemm2_kernel<<<g2blocks, 256, 0, stream>>>(bufY, B2h, B2l, bufX, N);
  agg_kernel<<<(N + 3) / 4, 256, 0, stream>>>(bufX, colp, csr, dinv, b2, bufY, N);
  pool_kernel<<<128, 256, 0, stream>>>(bufY, batch, pooled, N);
  cls_kernel<<<1, 256, 0, stream>>>(pooled, cw, cb, (float*)d_out);
}

// Round 6
// 497.216 us; speedup vs baseline: 1.2301x; 1.2301x over previous
//
#include <hip/hip_runtime.h>
#include <cstdint>
#include <cstddef>

typedef __attribute__((ext_vector_type(8))) short bf16x8;
typedef __attribute__((ext_vector_type(8))) _Float16 f16x8;
typedef __attribute__((ext_vector_type(4))) float f32x4;

// ---------------- bf16 split helpers (gemm2 path) ----------------

__device__ __forceinline__ unsigned bf_rne(float x) {
  unsigned u = __float_as_uint(x);
  return (u + 0x7FFFu + ((u >> 16) & 1u)) >> 16;
}

__device__ __forceinline__ void split1(float x, short& hi, short& lo) {
  unsigned hb = bf_rne(x);
  hi = (short)hb;
  float fh = __uint_as_float(hb << 16);
  lo = (short)bf_rne(x - fh);
}

__device__ __forceinline__ void split8(const float4& p, const float4& q, bf16x8& h, bf16x8& l) {
  short hh, ll;
  split1(p.x, hh, ll); h[0] = hh; l[0] = ll;
  split1(p.y, hh, ll); h[1] = hh; l[1] = ll;
  split1(p.z, hh, ll); h[2] = hh; l[2] = ll;
  split1(p.w, hh, ll); h[3] = hh; l[3] = ll;
  split1(q.x, hh, ll); h[4] = hh; l[4] = ll;
  split1(q.y, hh, ll); h[5] = hh; l[5] = ll;
  split1(q.z, hh, ll); h[6] = hh; l[6] = ll;
  split1(q.w, hh, ll); h[7] = hh; l[7] = ll;
}

__device__ __forceinline__ f16x8 cvt8(const float4& p, const float4& q) {
  f16x8 r;
  r[0] = (_Float16)p.x; r[1] = (_Float16)p.y; r[2] = (_Float16)p.z; r[3] = (_Float16)p.w;
  r[4] = (_Float16)q.x; r[5] = (_Float16)q.y; r[6] = (_Float16)q.z; r[7] = (_Float16)q.w;
  return r;
}

// ---------------- merged prep ----------------
// Bf (f16, gemm1): 896x64 fused weight = [Wf(768) | W1[0:64] | W1[64:80] | W1[112:128] | W1[128:144] | 0]
// fragment order: Bf[((chunk*4+g)*64 + col)*8 + j], j<4 <-> k=g*4+j, j>=4 <-> k=16+g*4+(j-4)
// biasf: llm_proj_b routed through W1.  B2h/B2l (split bf16, gemm2): same frag order.

__global__ void prep_kernel(const float* __restrict__ pw, const float* __restrict__ pb,
                            const float* __restrict__ w1, const float* __restrict__ w2,
                            _Float16* __restrict__ Bf, float* __restrict__ biasf,
                            short* __restrict__ B2h, short* __restrict__ B2l) {
  int idx = blockIdx.x * 256 + threadIdx.x;
  if (idx < 896 * 64) {
    int gk = idx >> 6, col = idx & 63;
    float val;
    if (gk < 768) {
      float acc = 0.0f;
      #pragma unroll 8
      for (int m = 0; m < 32; ++m) acc = fmaf(pw[gk * 32 + m], w1[(80 + m) * 64 + col], acc);
      val = acc;
    } else if (gk < 832) val = w1[(gk - 768) * 64 + col];
    else if (gk < 848)   val = w1[(64 + gk - 832) * 64 + col];
    else if (gk < 864)   val = w1[(112 + gk - 848) * 64 + col];
    else if (gk < 880)   val = w1[(128 + gk - 864) * 64 + col];
    else                 val = 0.0f;
    int chunk = gk >> 5, k = gk & 31;
    int g, j;
    if (k < 16) { g = k >> 2; j = k & 3; } else { int k2 = k - 16; g = k2 >> 2; j = 4 + (k2 & 3); }
    Bf[((size_t)(chunk * 4 + g) * 64 + col) * 8 + j] = (_Float16)val;
  } else if (idx < 896 * 64 + 64) {
    int col = idx - 896 * 64;
    float acc = 0.0f;
    for (int m = 0; m < 32; ++m) acc = fmaf(pb[m], w1[(80 + m) * 64 + col], acc);
    biasf[col] = acc;
  } else if (idx < 896 * 64 + 64 + 64 * 64) {
    int q2 = idx - (896 * 64 + 64);
    int gk = q2 >> 6, col = q2 & 63;
    float val = w2[gk * 64 + col];
    int chunk = gk >> 5, k = gk & 31;
    int g, j;
    if (k < 16) { g = k >> 2; j = k & 3; } else { int k2 = k - 16; g = k2 >> 2; j = 4 + (k2 & 3); }
    size_t o = ((size_t)(chunk * 4 + g) * 64 + col) * 8 + j;
    short hh, ll; split1(val, hh, ll);
    B2h[o] = hh; B2l[o] = ll;
  }
}

// ---------------- CSR build (raw edge weights; dinv folded into gemm epilogues) ----------------

__global__ void cnt_kernel(const int* __restrict__ ei, int* __restrict__ cnt, int E) {
  int e = blockIdx.x * 256 + threadIdx.x;
  if (e < E) atomicAdd(&cnt[ei[E + e]], 1);
}

__global__ __launch_bounds__(256) void scan_blk(const int* __restrict__ cnt,
                                                int* __restrict__ colp,
                                                int* __restrict__ bsum, int n) {
  __shared__ int ws[4];
  int t = threadIdx.x, lane = t & 63, w = t >> 6;
  int i = blockIdx.x * 256 + t;
  int v = (i < n) ? cnt[i] : 0;
  int x = v;
  #pragma unroll
  for (int off = 1; off < 64; off <<= 1) { int y = __shfl_up(x, off); if (lane >= off) x += y; }
  if (lane == 63) ws[w] = x;
  __syncthreads();
  if (t == 0) {
    int s = 0;
    #pragma unroll
    for (int k = 0; k < 4; ++k) { int tmp = ws[k]; ws[k] = s; s += tmp; }
    bsum[blockIdx.x] = s;
  }
  __syncthreads();
  if (i < n) colp[i] = ws[w] + x - v;
}

__global__ __launch_bounds__(512) void scan_top(int* __restrict__ bsum,
                                                int* __restrict__ colp, int nb, int n) {
  __shared__ int ws[8];
  int t = threadIdx.x, lane = t & 63, w = t >> 6;
  int v = (t < nb) ? bsum[t] : 0;
  int x = v;
  #pragma unroll
  for (int off = 1; off < 64; off <<= 1) { int y = __shfl_up(x, off); if (lane >= off) x += y; }
  if (lane == 63) ws[w] = x;
  __syncthreads();
  if (t == 0) {
    int s = 0;
    #pragma unroll
    for (int k = 0; k < 8; ++k) { int tmp = ws[k]; ws[k] = s; s += tmp; }
  }
  __syncthreads();
  int excl = ws[w] + x - v;
  if (t < nb) bsum[t] = excl;
  if (t == nb - 1) colp[n] = excl + v;
}

__global__ void scan_add(int* __restrict__ colp, int* __restrict__ fillp,
                         const int* __restrict__ bsum, int n) {
  int i = blockIdx.x * 256 + threadIdx.x;
  if (i < n) {
    int c = colp[i] + bsum[blockIdx.x];
    colp[i] = c;
    fillp[i] = c;
  }
}

__global__ void fill_kernel(const int* __restrict__ ei, const float* __restrict__ ew,
                            int* __restrict__ fillp, int2* __restrict__ csr, int E) {
  int e = blockIdx.x * 256 + threadIdx.x;
  if (e >= E) return;
  int row = ei[e], col = ei[E + e];
  int pos = atomicAdd(&fillp[col], 1);
  csr[pos] = make_int2(row, __float_as_int(ew[e]));
}

// dinv[j] = rsqrt(1 + sum of in-edge weights) — coalesced CSR sweep
__global__ void degsum_kernel(const int* __restrict__ colp, const int2* __restrict__ csr,
                              float* __restrict__ dinv, int n) {
  int j = blockIdx.x * 256 + threadIdx.x;
  if (j >= n) return;
  int e0 = colp[j], e1 = colp[j + 1];
  float s = 1.0f;
  for (int e = e0; e < e1; ++e) s += __int_as_float(csr[e].y);
  dinv[j] = rsqrtf(s);
}

// ---------------- gemm1: f16 streaming MFMA, 3-deep register pipeline ----------------
// wave owns 32 rows x 64 cols; epilogue scales by dinv[row] (h' = dinv * (x@W1 + biasf))

__device__ __forceinline__ void loadBf(const _Float16* __restrict__ Bf, int c, int g, int r16,
                                       f16x8 (&bf)[4]) {
  #pragma unroll
  for (int ct = 0; ct < 4; ++ct)
    bf[ct] = *(const f16x8*)(Bf + ((size_t)(c * 4 + g) * 64 + ct * 16 + r16) * 8);
}

__device__ __forceinline__ void mfma8(f32x4 (&acc)[2][4], const f16x8& a0, const f16x8& a1,
                                      const f16x8 (&bf)[4]) {
  #pragma unroll
  for (int ct = 0; ct < 4; ++ct) {
    acc[0][ct] = __builtin_amdgcn_mfma_f32_16x16x32_f16(a0, bf[ct], acc[0][ct], 0, 0, 0);
    acc[1][ct] = __builtin_amdgcn_mfma_f32_16x16x32_f16(a1, bf[ct], acc[1][ct], 0, 0, 0);
  }
}

__global__ __launch_bounds__(256, 3) void gemm1_kernel(
    const float* __restrict__ llm, const _Float16* __restrict__ Bf,
    const int* __restrict__ names, const int* __restrict__ types,
    const float* __restrict__ beh, const float* __restrict__ nemb,
    const float* __restrict__ temb, const float* __restrict__ biasf,
    const float* __restrict__ dinv, float* __restrict__ out, int n)
{
  // bijective XCD swizzle
  int nwg = gridDim.x;
  int b = blockIdx.x;
  int q = nwg >> 3, r = nwg & 7;
  int xcd = b & 7, bidx = b >> 3;
  int swz = (xcd < r ? xcd * (q + 1) : r * (q + 1) + (xcd - r) * q) + bidx;

  int w = swz * 4 + (threadIdx.x >> 6);
  int nw = (n + 31) >> 5;
  if (w >= nw) return;
  int lane = threadIdx.x & 63;
  int g = lane >> 4, r16 = lane & 15;
  int base = w * 32;

  int arow0 = base + r16;      if (arow0 > n - 1) arow0 = n - 1;   // clamp; stores guarded
  int arow1 = base + 16 + r16; if (arow1 > n - 1) arow1 = n - 1;
  int nm0 = names[arow0], nm1 = names[arow1];
  int tp0 = types[arow0], tp1 = types[arow1];

  const float* pA0 = llm + (size_t)arow0 * 768 + g * 4;
  const float* pA1 = llm + (size_t)arow1 * 768 + g * 4;

  f32x4 acc[2][4];
  #pragma unroll
  for (int i = 0; i < 2; ++i)
    #pragma unroll
    for (int j = 0; j < 4; ++j) { acc[i][j][0] = 0.f; acc[i][j][1] = 0.f; acc[i][j][2] = 0.f; acc[i][j][3] = 0.f; }

  // 3-deep pipeline buffers (chunks c, c+1, c+2)
  float4 X0l = *(const float4*)(pA0 +  0), X0h = *(const float4*)(pA0 + 16);
  float4 X1l = *(const float4*)(pA1 +  0), X1h = *(const float4*)(pA1 + 16);
  float4 Y0l = *(const float4*)(pA0 + 32), Y0h = *(const float4*)(pA0 + 48);
  float4 Y1l = *(const float4*)(pA1 + 32), Y1h = *(const float4*)(pA1 + 48);
  float4 Z0l = *(const float4*)(pA0 + 64), Z0h = *(const float4*)(pA0 + 80);
  float4 Z1l = *(const float4*)(pA1 + 64), Z1h = *(const float4*)(pA1 + 96 - 16);

  f16x8 bf[4], a0, a1;

  #pragma unroll 1
  for (int cc = 0; cc < 7; ++cc) {
    const int c = cc * 3;
    // consume X (chunk c), prefetch c+3 -> X
    loadBf(Bf, c, g, r16, bf);
    a0 = cvt8(X0l, X0h); a1 = cvt8(X1l, X1h);
    X0l = *(const float4*)(pA0 + (c + 3) * 32);
    X0h = *(const float4*)(pA0 + (c + 3) * 32 + 16);
    X1l = *(const float4*)(pA1 + (c + 3) * 32);
    X1h = *(const float4*)(pA1 + (c + 3) * 32 + 16);
    __builtin_amdgcn_sched_barrier(0);
    mfma8(acc, a0, a1, bf);
    // consume Y (chunk c+1), prefetch c+4 -> Y
    loadBf(Bf, c + 1, g, r16, bf);
    a0 = cvt8(Y0l, Y0h); a1 = cvt8(Y1l, Y1h);
    Y0l = *(const float4*)(pA0 + (c + 4) * 32);
    Y0h = *(const float4*)(pA0 + (c + 4) * 32 + 16);
    Y1l = *(const float4*)(pA1 + (c + 4) * 32);
    Y1h = *(const float4*)(pA1 + (c + 4) * 32 + 16);
    __builtin_amdgcn_sched_barrier(0);
    mfma8(acc, a0, a1, bf);
    // consume Z (chunk c+2), prefetch c+5 -> Z
    loadBf(Bf, c + 2, g, r16, bf);
    a0 = cvt8(Z0l, Z0h); a1 = cvt8(Z1l, Z1h);
    Z0l = *(const float4*)(pA0 + (c + 5) * 32);
    Z0h = *(const float4*)(pA0 + (c + 5) * 32 + 16);
    Z1l = *(const float4*)(pA1 + (c + 5) * 32);
    Z1h = *(const float4*)(pA1 + (c + 5) * 32 + 16);
    __builtin_amdgcn_sched_barrier(0);
    mfma8(acc, a0, a1, bf);
  }

  // chunks 21, 22, 23 already in X/Y/Z
  loadBf(Bf, 21, g, r16, bf);
  a0 = cvt8(X0l, X0h); a1 = cvt8(X1l, X1h);
  mfma8(acc, a0, a1, bf);
  loadBf(Bf, 22, g, r16, bf);
  a0 = cvt8(Y0l, Y0h); a1 = cvt8(Y1l, Y1h);
  mfma8(acc, a0, a1, bf);
  loadBf(Bf, 23, g, r16, bf);
  a0 = cvt8(Z0l, Z0h); a1 = cvt8(Z1l, Z1h);
  mfma8(acc, a0, a1, bf);

  // tail: 24/25 = name_emb, 26 = type|behav[0:16], 27 = behav[16:32]|0
  const float* pN0 = nemb + (size_t)nm0 * 64 + g * 4;
  const float* pN1 = nemb + (size_t)nm1 * 64 + g * 4;
  #pragma unroll
  for (int t = 0; t < 2; ++t) {
    float4 l0 = *(const float4*)(pN0 + t * 32), h0 = *(const float4*)(pN0 + t * 32 + 16);
    float4 l1 = *(const float4*)(pN1 + t * 32), h1 = *(const float4*)(pN1 + t * 32 + 16);
    loadBf(Bf, 24 + t, g, r16, bf);
    a0 = cvt8(l0, h0); a1 = cvt8(l1, h1);
    mfma8(acc, a0, a1, bf);
  }
  {
    float4 l0 = *(const float4*)(temb + (size_t)tp0 * 16 + g * 4);
    float4 h0 = *(const float4*)(beh + (size_t)arow0 * 32 + g * 4);
    float4 l1 = *(const float4*)(temb + (size_t)tp1 * 16 + g * 4);
    float4 h1 = *(const float4*)(beh + (size_t)arow1 * 32 + g * 4);
    loadBf(Bf, 26, g, r16, bf);
    a0 = cvt8(l0, h0); a1 = cvt8(l1, h1);
    mfma8(acc, a0, a1, bf);
  }
  {
    const float4 z = make_float4(0.f, 0.f, 0.f, 0.f);
    float4 l0 = *(const float4*)(beh + (size_t)arow0 * 32 + 16 + g * 4);
    float4 l1 = *(const float4*)(beh + (size_t)arow1 * 32 + 16 + g * 4);
    loadBf(Bf, 27, g, r16, bf);
    a0 = cvt8(l0, z); a1 = cvt8(l1, z);
    mfma8(acc, a0, a1, bf);
  }

  // epilogue: out = (acc + biasf) * dinv[node]
  float dv0[4], dv1[4];
  #pragma unroll
  for (int rr = 0; rr < 4; ++rr) {
    int n0 = base + g * 4 + rr;      dv0[rr] = dinv[n0 < n ? n0 : n - 1];
    int n1 = base + 16 + g * 4 + rr; dv1[rr] = dinv[n1 < n ? n1 : n - 1];
  }
  #pragma unroll
  for (int ct = 0; ct < 4; ++ct) {
    int col = ct * 16 + r16;
    float bfc = biasf[col];
    #pragma unroll
    for (int rr = 0; rr < 4; ++rr) {
      int node0 = base + g * 4 + rr;
      if (node0 < n) out[(size_t)node0 * 64 + col] = (acc[0][ct][rr] + bfc) * dv0[rr];
      int node1 = base + 16 + g * 4 + rr;
      if (node1 < n) out[(size_t)node1 * 64 + col] = (acc[1][ct][rr] + bfc) * dv1[rr];
    }
  }
}

// ---------------- gemm2: split-bf16, K=64, epilogue * dinv ----------------

__device__ __forceinline__ void loadB2(const short* __restrict__ Bh, const short* __restrict__ Bl,
                                       int c, int g, int r16, bf16x8 (&bh)[4], bf16x8 (&bl)[4]) {
  #pragma unroll
  for (int ct = 0; ct < 4; ++ct) {
    size_t o = ((size_t)(c * 4 + g) * 64 + ct * 16 + r16) * 8;
    bh[ct] = *(const bf16x8*)(Bh + o);
    bl[ct] = *(const bf16x8*)(Bl + o);
  }
}

__global__ __launch_bounds__(256, 4) void gemm2_kernel(
    const float* __restrict__ h, const short* __restrict__ B2h, const short* __restrict__ B2l,
    const float* __restrict__ dinv, float* __restrict__ out, int n)
{
  int w = blockIdx.x * 4 + (threadIdx.x >> 6);
  int nw = (n + 31) >> 5;
  if (w >= nw) return;
  int lane = threadIdx.x & 63;
  int g = lane >> 4, r16 = lane & 15;
  int base = w * 32;
  int arow0 = base + r16;      if (arow0 > n - 1) arow0 = n - 1;
  int arow1 = base + 16 + r16; if (arow1 > n - 1) arow1 = n - 1;

  f32x4 acc[2][4];
  #pragma unroll
  for (int i = 0; i < 2; ++i)
    #pragma unroll
    for (int j = 0; j < 4; ++j) { acc[i][j][0] = 0.f; acc[i][j][1] = 0.f; acc[i][j][2] = 0.f; acc[i][j][3] = 0.f; }

  #pragma unroll
  for (int c = 0; c < 2; ++c) {
    bf16x8 bh[4], bl[4];
    loadB2(B2h, B2l, c, g, r16, bh, bl);
    const float* p0 = h + (size_t)arow0 * 64 + c * 32 + g * 4;
    const float* p1 = h + (size_t)arow1 * 64 + c * 32 + g * 4;
    float4 lo0 = *(const float4*)p0, hi0 = *(const float4*)(p0 + 16);
    float4 lo1 = *(const float4*)p1, hi1 = *(const float4*)(p1 + 16);
    bf16x8 ah0, al0, ah1, al1;
    split8(lo0, hi0, ah0, al0);
    split8(lo1, hi1, ah1, al1);
    #pragma unroll
    for (int ct = 0; ct < 4; ++ct) {
      acc[0][ct] = __builtin_amdgcn_mfma_f32_16x16x32_bf16(ah0, bh[ct], acc[0][ct], 0, 0, 0);
      acc[0][ct] = __builtin_amdgcn_mfma_f32_16x16x32_bf16(ah0, bl[ct], acc[0][ct], 0, 0, 0);
      acc[0][ct] = __builtin_amdgcn_mfma_f32_16x16x32_bf16(al0, bh[ct], acc[0][ct], 0, 0, 0);
    }
    #pragma unroll
    for (int ct = 0; ct < 4; ++ct) {
      acc[1][ct] = __builtin_amdgcn_mfma_f32_16x16x32_bf16(ah1, bh[ct], acc[1][ct], 0, 0, 0);
      acc[1][ct] = __builtin_amdgcn_mfma_f32_16x16x32_bf16(ah1, bl[ct], acc[1][ct], 0, 0, 0);
      acc[1][ct] = __builtin_amdgcn_mfma_f32_16x16x32_bf16(al1, bh[ct], acc[1][ct], 0, 0, 0);
    }
  }

  float dv0[4], dv1[4];
  #pragma unroll
  for (int rr = 0; rr < 4; ++rr) {
    int n0 = base + g * 4 + rr;      dv0[rr] = dinv[n0 < n ? n0 : n - 1];
    int n1 = base + 16 + g * 4 + rr; dv1[rr] = dinv[n1 < n ? n1 : n - 1];
  }
  #pragma unroll
  for (int ct = 0; ct < 4; ++ct) {
    int col = ct * 16 + r16;
    #pragma unroll
    for (int rr = 0; rr < 4; ++rr) {
      int node0 = base + g * 4 + rr;
      if (node0 < n) out[(size_t)node0 * 64 + col] = acc[0][ct][rr] * dv0[rr];
      int node1 = base + 16 + g * 4 + rr;
      if (node1 < n) out[(size_t)node1 * 64 + col] = acc[1][ct][rr] * dv1[rr];
    }
  }
}

// ---------------- aggregation: out[j] = relu(bias + dj*(hp[j] + sum ew*hp[src])) ----------------
// hp is the dinv-prescaled hidden state; csr holds raw ew. unroll 8, dual accumulators.

__global__ __launch_bounds__(256) void agg_kernel(
    const float* __restrict__ hp, const int* __restrict__ colp,
    const int2* __restrict__ csr, const float* __restrict__ dinv,
    const float* __restrict__ bias, float* __restrict__ out, int n)
{
  int wid = threadIdx.x >> 6, lane = threadIdx.x & 63;
  int j = blockIdx.x * 4 + wid;
  if (j >= n) return;
  float dj = dinv[j];
  float hj = hp[(size_t)j * 64 + lane];
  int e0 = colp[j], e1 = colp[j + 1];
  float s0 = 0.0f, s1 = 0.0f;
  int e = e0;
  for (; e + 8 <= e1; e += 8) {
    int2 m0 = csr[e],     m1 = csr[e + 1], m2 = csr[e + 2], m3 = csr[e + 3];
    int2 m4 = csr[e + 4], m5 = csr[e + 5], m6 = csr[e + 6], m7 = csr[e + 7];
    float f0 = hp[(size_t)m0.x * 64 + lane];
    float f1 = hp[(size_t)m1.x * 64 + lane];
    float f2 = hp[(size_t)m2.x * 64 + lane];
    float f3 = hp[(size_t)m3.x * 64 + lane];
    float f4 = hp[(size_t)m4.x * 64 + lane];
    float f5 = hp[(size_t)m5.x * 64 + lane];
    float f6 = hp[(size_t)m6.x * 64 + lane];
    float f7 = hp[(size_t)m7.x * 64 + lane];
    s0 = fmaf(__int_as_float(m0.y), f0, s0);
    s1 = fmaf(__int_as_float(m1.y), f1, s1);
    s0 = fmaf(__int_as_float(m2.y), f2, s0);
    s1 = fmaf(__int_as_float(m3.y), f3, s1);
    s0 = fmaf(__int_as_float(m4.y), f4, s0);
    s1 = fmaf(__int_as_float(m5.y), f5, s1);
    s0 = fmaf(__int_as_float(m6.y), f6, s0);
    s1 = fmaf(__int_as_float(m7.y), f7, s1);
  }
  for (; e + 2 <= e1; e += 2) {
    int2 m0 = csr[e], m1 = csr[e + 1];
    float f0 = hp[(size_t)m0.x * 64 + lane];
    float f1 = hp[(size_t)m1.x * 64 + lane];
    s0 = fmaf(__int_as_float(m0.y), f0, s0);
    s1 = fmaf(__int_as_float(m1.y), f1, s1);
  }
  if (e < e1) {
    int2 m = csr[e];
    s0 = fmaf(__int_as_float(m.y), hp[(size_t)m.x * 64 + lane], s0);
  }
  float acc = bias[lane] + dj * (hj + s0 + s1);
  out[(size_t)j * 64 + lane] = fmaxf(acc, 0.0f);
}

// ---------------- pool + classifier ----------------

__global__ __launch_bounds__(256) void pool_kernel(const float* __restrict__ x,
                                                   const int* __restrict__ batch,
                                                   float* __restrict__ pooled, int n) {
  __shared__ float red[4][64];
  __shared__ int range_s[2];
  int gph = blockIdx.x;
  int tid = threadIdx.x, wid = tid >> 6, lane = tid & 63;
  if (tid < 2) {
    int target = gph + tid;
    int lo = 0, hi = n;
    while (lo < hi) { int m = (lo + hi) >> 1; if (batch[m] < target) lo = m + 1; else hi = m; }
    range_s[tid] = lo;
  }
  __syncthreads();
  int lo = range_s[0], hi = range_s[1];
  float acc = 0.0f;
  for (int i = lo + wid; i < hi; i += 4) acc += x[(size_t)i * 64 + lane];
  red[wid][lane] = acc;
  __syncthreads();
  if (tid < 64) {
    float sum = red[0][lane] + red[1][lane] + red[2][lane] + red[3][lane];
    float cntf = (float)(hi - lo);
    pooled[gph * 64 + lane] = sum / fmaxf(cntf, 1.0f);
  }
}

__global__ void cls_kernel(const float* __restrict__ pooled, const float* __restrict__ cw,
                           const float* __restrict__ cb, float* __restrict__ out) {
  int t = threadIdx.x;
  int gph = t >> 1, c = t & 1;
  float acc = cb[c];
  #pragma unroll 8
  for (int k = 0; k < 64; ++k) acc = fmaf(pooled[gph * 64 + k], cw[k * 2 + c], acc);
  out[gph * 2 + c] = acc;
}

// ---------------- launch ----------------

extern "C" void kernel_launch(void* const* d_in, const int* in_sizes, int n_in,
                              void* d_out, int out_size, void* d_ws, size_t ws_size,
                              hipStream_t stream) {
  const int*   x_names  = (const int*)  d_in[0];
  const int*   x_types  = (const int*)  d_in[1];
  const float* behav    = (const float*)d_in[2];
  const int*   ei       = (const int*)  d_in[3];
  const float* ew       = (const float*)d_in[4];
  const int*   batch    = (const int*)  d_in[5];
  const float* llm      = (const float*)d_in[6];
  const float* name_emb = (const float*)d_in[7];
  const float* type_emb = (const float*)d_in[8];
  const float* pw       = (const float*)d_in[9];
  const float* pb       = (const float*)d_in[10];
  const float* w1       = (const float*)d_in[11];
  const float* b1       = (const float*)d_in[12];
  const float* w2       = (const float*)d_in[13];
  const float* b2       = (const float*)d_in[14];
  const float* cw       = (const float*)d_in[15];
  const float* cb       = (const float*)d_in[16];

  const int N = in_sizes[0];
  const int E = in_sizes[4];
  const int nb = (N + 255) / 256;
  const int eb = (E + 255) / 256;
  const int gblocks = ((N + 31) / 32 + 3) / 4;

  char* p = (char*)d_ws;
  auto alloc = [&](size_t bytes) -> void* {
    void* r = (void*)p; p += (bytes + 255) & ~(size_t)255; return r;
  };
  float*     dinv   = (float*)    alloc((size_t)N * 4);
  int*       cnt    = (int*)      alloc((size_t)N * 4);
  int*       colp   = (int*)      alloc((size_t)(N + 1) * 4);
  int*       fillp  = (int*)      alloc((size_t)N * 4);
  int2*      csr    = (int2*)     alloc((size_t)E * 8);
  int*       bsum   = (int*)      alloc((size_t)(nb + 1) * 4);
  _Float16*  Bf     = (_Float16*) alloc((size_t)896 * 64 * 2);
  short*     B2h    = (short*)    alloc((size_t)64 * 64 * 2);
  short*     B2l    = (short*)    alloc((size_t)64 * 64 * 2);
  float*     biasf  = (float*)    alloc((size_t)64 * 4);
  float*     bufX   = (float*)    alloc((size_t)N * 64 * 4);
  float*     bufY   = (float*)    alloc((size_t)N * 64 * 4);
  float*     pooled = (float*)    alloc((size_t)128 * 64 * 4);
  (void)ws_size; (void)n_in; (void)out_size;

  prep_kernel<<<(896 * 64 + 64 + 64 * 64 + 255) / 256, 256, 0, stream>>>(
      pw, pb, w1, w2, Bf, biasf, B2h, B2l);
  hipMemsetAsync(cnt, 0, (size_t)N * 4, stream);
  cnt_kernel<<<eb, 256, 0, stream>>>(ei, cnt, E);
  scan_blk<<<nb, 256, 0, stream>>>(cnt, colp, bsum, N);
  scan_top<<<1, 512, 0, stream>>>(bsum, colp, nb, N);
  scan_add<<<nb, 256, 0, stream>>>(colp, fillp, bsum, N);
  fill_kernel<<<eb, 256, 0, stream>>>(ei, ew, fillp, csr, E);
  degsum_kernel<<<nb, 256, 0, stream>>>(colp, csr, dinv, N);

  gemm1_kernel<<<gblocks, 256, 0, stream>>>(llm, Bf, x_names, x_types, behav,
                                            name_emb, type_emb, biasf, dinv, bufX, N);
  agg_kernel<<<(N + 3) / 4, 256, 0, stream>>>(bufX, colp, csr, dinv, b1, bufY, N);
  gemm2_kernel<<<gblocks, 256, 0, stream>>>(bufY, B2h, B2l, dinv, bufX, N);
  agg_kernel<<<(N + 3) / 4, 256, 0, stream>>>(bufX, colp, csr, dinv, b2, bufY, N);
  pool_kernel<<<128, 256, 0, stream>>>(bufY, batch, pooled, N);
  cls_kernel<<<1, 256, 0, stream>>>(pooled, cw, cb, (float*)d_out);
}

// Round 7
// 474.422 us; speedup vs baseline: 1.2892x; 1.0480x over previous
//
#include <hip/hip_runtime.h>
#include <cstdint>
#include <cstddef>

typedef __attribute__((ext_vector_type(8))) _Float16 f16x8;
typedef __attribute__((ext_vector_type(4))) _Float16 f16x4;
typedef __attribute__((ext_vector_type(4))) float f32x4;

__device__ __forceinline__ f16x8 cvt8(const float4& p, const float4& q) {
  f16x8 r;
  r[0] = (_Float16)p.x; r[1] = (_Float16)p.y; r[2] = (_Float16)p.z; r[3] = (_Float16)p.w;
  r[4] = (_Float16)q.x; r[5] = (_Float16)q.y; r[6] = (_Float16)q.z; r[7] = (_Float16)q.w;
  return r;
}

// ---------------- merged prep ----------------
// Bf (f16, gemm1): 896x64 fused weight = [Wf(768) | W1[0:64] | W1[64:80] | W1[112:128] | W1[128:144] | 0]
// fragment order: Bf[((chunk*4+g)*64 + col)*8 + j], j<4 <-> k=g*4+j, j>=4 <-> k=16+g*4+(j-4)
// biasf: llm_proj_b routed through W1.  B2f (f16, gemm2): same frag order.

__global__ void prep_kernel(const float* __restrict__ pw, const float* __restrict__ pb,
                            const float* __restrict__ w1, const float* __restrict__ w2,
                            _Float16* __restrict__ Bf, float* __restrict__ biasf,
                            _Float16* __restrict__ B2f) {
  int idx = blockIdx.x * 256 + threadIdx.x;
  if (idx < 896 * 64) {
    int gk = idx >> 6, col = idx & 63;
    float val;
    if (gk < 768) {
      float acc = 0.0f;
      #pragma unroll 8
      for (int m = 0; m < 32; ++m) acc = fmaf(pw[gk * 32 + m], w1[(80 + m) * 64 + col], acc);
      val = acc;
    } else if (gk < 832) val = w1[(gk - 768) * 64 + col];
    else if (gk < 848)   val = w1[(64 + gk - 832) * 64 + col];
    else if (gk < 864)   val = w1[(112 + gk - 848) * 64 + col];
    else if (gk < 880)   val = w1[(128 + gk - 864) * 64 + col];
    else                 val = 0.0f;
    int chunk = gk >> 5, k = gk & 31;
    int g, j;
    if (k < 16) { g = k >> 2; j = k & 3; } else { int k2 = k - 16; g = k2 >> 2; j = 4 + (k2 & 3); }
    Bf[((size_t)(chunk * 4 + g) * 64 + col) * 8 + j] = (_Float16)val;
  } else if (idx < 896 * 64 + 64) {
    int col = idx - 896 * 64;
    float acc = 0.0f;
    for (int m = 0; m < 32; ++m) acc = fmaf(pb[m], w1[(80 + m) * 64 + col], acc);
    biasf[col] = acc;
  } else if (idx < 896 * 64 + 64 + 64 * 64) {
    int q2 = idx - (896 * 64 + 64);
    int gk = q2 >> 6, col = q2 & 63;
    float val = w2[gk * 64 + col];
    int chunk = gk >> 5, k = gk & 31;
    int g, j;
    if (k < 16) { g = k >> 2; j = k & 3; } else { int k2 = k - 16; g = k2 >> 2; j = 4 + (k2 & 3); }
    B2f[((size_t)(chunk * 4 + g) * 64 + col) * 8 + j] = (_Float16)val;
  }
}

// ---------------- CSR build (raw edge weights; dinv folded into gemm epilogues) ----------------

__global__ void cnt_kernel(const int* __restrict__ ei, int* __restrict__ cnt, int E) {
  int e = blockIdx.x * 256 + threadIdx.x;
  if (e < E) atomicAdd(&cnt[ei[E + e]], 1);
}

__global__ __launch_bounds__(256) void scan_blk(const int* __restrict__ cnt,
                                                int* __restrict__ colp,
                                                int* __restrict__ bsum, int n) {
  __shared__ int ws[4];
  int t = threadIdx.x, lane = t & 63, w = t >> 6;
  int i = blockIdx.x * 256 + t;
  int v = (i < n) ? cnt[i] : 0;
  int x = v;
  #pragma unroll
  for (int off = 1; off < 64; off <<= 1) { int y = __shfl_up(x, off); if (lane >= off) x += y; }
  if (lane == 63) ws[w] = x;
  __syncthreads();
  if (t == 0) {
    int s = 0;
    #pragma unroll
    for (int k = 0; k < 4; ++k) { int tmp = ws[k]; ws[k] = s; s += tmp; }
    bsum[blockIdx.x] = s;
  }
  __syncthreads();
  if (i < n) colp[i] = ws[w] + x - v;
}

__global__ __launch_bounds__(512) void scan_top(int* __restrict__ bsum,
                                                int* __restrict__ colp, int nb, int n) {
  __shared__ int ws[8];
  int t = threadIdx.x, lane = t & 63, w = t >> 6;
  int v = (t < nb) ? bsum[t] : 0;
  int x = v;
  #pragma unroll
  for (int off = 1; off < 64; off <<= 1) { int y = __shfl_up(x, off); if (lane >= off) x += y; }
  if (lane == 63) ws[w] = x;
  __syncthreads();
  if (t == 0) {
    int s = 0;
    #pragma unroll
    for (int k = 0; k < 8; ++k) { int tmp = ws[k]; ws[k] = s; s += tmp; }
  }
  __syncthreads();
  int excl = ws[w] + x - v;
  if (t < nb) bsum[t] = excl;
  if (t == nb - 1) colp[n] = excl + v;
}

__global__ void scan_add(int* __restrict__ colp, int* __restrict__ fillp,
                         const int* __restrict__ bsum, int n) {
  int i = blockIdx.x * 256 + threadIdx.x;
  if (i < n) {
    int c = colp[i] + bsum[blockIdx.x];
    colp[i] = c;
    fillp[i] = c;
  }
}

__global__ void fill_kernel(const int* __restrict__ ei, const float* __restrict__ ew,
                            int* __restrict__ fillp, int2* __restrict__ csr, int E) {
  int e = blockIdx.x * 256 + threadIdx.x;
  if (e >= E) return;
  int row = ei[e], col = ei[E + e];
  int pos = atomicAdd(&fillp[col], 1);
  csr[pos] = make_int2(row, __float_as_int(ew[e]));
}

// dinv[j] = rsqrt(1 + sum of in-edge weights) — coalesced CSR sweep
__global__ void degsum_kernel(const int* __restrict__ colp, const int2* __restrict__ csr,
                              float* __restrict__ dinv, int n) {
  int j = blockIdx.x * 256 + threadIdx.x;
  if (j >= n) return;
  int e0 = colp[j], e1 = colp[j + 1];
  float s = 1.0f;
  for (int e = e0; e < e1; ++e) s += __int_as_float(csr[e].y);
  dinv[j] = rsqrtf(s);
}

// ---------------- gemm1: f16 streaming MFMA, 3-deep register pipeline ----------------
// wave owns 32 rows x 64 cols; epilogue: hp = dinv*(x@W1 + biasf), stored f16

__device__ __forceinline__ void loadBf(const _Float16* __restrict__ Bf, int c, int g, int r16,
                                       f16x8 (&bf)[4]) {
  #pragma unroll
  for (int ct = 0; ct < 4; ++ct)
    bf[ct] = *(const f16x8*)(Bf + ((size_t)(c * 4 + g) * 64 + ct * 16 + r16) * 8);
}

__device__ __forceinline__ void mfma8(f32x4 (&acc)[2][4], const f16x8& a0, const f16x8& a1,
                                      const f16x8 (&bf)[4]) {
  #pragma unroll
  for (int ct = 0; ct < 4; ++ct) {
    acc[0][ct] = __builtin_amdgcn_mfma_f32_16x16x32_f16(a0, bf[ct], acc[0][ct], 0, 0, 0);
    acc[1][ct] = __builtin_amdgcn_mfma_f32_16x16x32_f16(a1, bf[ct], acc[1][ct], 0, 0, 0);
  }
}

__global__ __launch_bounds__(256, 3) void gemm1_kernel(
    const float* __restrict__ llm, const _Float16* __restrict__ Bf,
    const int* __restrict__ names, const int* __restrict__ types,
    const float* __restrict__ beh, const float* __restrict__ nemb,
    const float* __restrict__ temb, const float* __restrict__ biasf,
    const float* __restrict__ dinv, _Float16* __restrict__ out, int n)
{
  // bijective XCD swizzle
  int nwg = gridDim.x;
  int b = blockIdx.x;
  int q = nwg >> 3, r = nwg & 7;
  int xcd = b & 7, bidx = b >> 3;
  int swz = (xcd < r ? xcd * (q + 1) : r * (q + 1) + (xcd - r) * q) + bidx;

  int w = swz * 4 + (threadIdx.x >> 6);
  int nw = (n + 31) >> 5;
  if (w >= nw) return;
  int lane = threadIdx.x & 63;
  int g = lane >> 4, r16 = lane & 15;
  int base = w * 32;

  int arow0 = base + r16;      if (arow0 > n - 1) arow0 = n - 1;   // clamp; stores guarded
  int arow1 = base + 16 + r16; if (arow1 > n - 1) arow1 = n - 1;
  int nm0 = names[arow0], nm1 = names[arow1];
  int tp0 = types[arow0], tp1 = types[arow1];

  const float* pA0 = llm + (size_t)arow0 * 768 + g * 4;
  const float* pA1 = llm + (size_t)arow1 * 768 + g * 4;

  f32x4 acc[2][4];
  #pragma unroll
  for (int i = 0; i < 2; ++i)
    #pragma unroll
    for (int j = 0; j < 4; ++j) { acc[i][j][0] = 0.f; acc[i][j][1] = 0.f; acc[i][j][2] = 0.f; acc[i][j][3] = 0.f; }

  // 3-deep pipeline buffers (chunks c, c+1, c+2)
  float4 X0l = *(const float4*)(pA0 +  0), X0h = *(const float4*)(pA0 + 16);
  float4 X1l = *(const float4*)(pA1 +  0), X1h = *(const float4*)(pA1 + 16);
  float4 Y0l = *(const float4*)(pA0 + 32), Y0h = *(const float4*)(pA0 + 48);
  float4 Y1l = *(const float4*)(pA1 + 32), Y1h = *(const float4*)(pA1 + 48);
  float4 Z0l = *(const float4*)(pA0 + 64), Z0h = *(const float4*)(pA0 + 80);
  float4 Z1l = *(const float4*)(pA1 + 64), Z1h = *(const float4*)(pA1 + 80);

  f16x8 bf[4], a0, a1;

  #pragma unroll 1
  for (int cc = 0; cc < 7; ++cc) {
    const int c = cc * 3;
    loadBf(Bf, c, g, r16, bf);
    a0 = cvt8(X0l, X0h); a1 = cvt8(X1l, X1h);
    X0l = *(const float4*)(pA0 + (c + 3) * 32);
    X0h = *(const float4*)(pA0 + (c + 3) * 32 + 16);
    X1l = *(const float4*)(pA1 + (c + 3) * 32);
    X1h = *(const float4*)(pA1 + (c + 3) * 32 + 16);
    __builtin_amdgcn_sched_barrier(0);
    mfma8(acc, a0, a1, bf);
    loadBf(Bf, c + 1, g, r16, bf);
    a0 = cvt8(Y0l, Y0h); a1 = cvt8(Y1l, Y1h);
    Y0l = *(const float4*)(pA0 + (c + 4) * 32);
    Y0h = *(const float4*)(pA0 + (c + 4) * 32 + 16);
    Y1l = *(const float4*)(pA1 + (c + 4) * 32);
    Y1h = *(const float4*)(pA1 + (c + 4) * 32 + 16);
    __builtin_amdgcn_sched_barrier(0);
    mfma8(acc, a0, a1, bf);
    loadBf(Bf, c + 2, g, r16, bf);
    a0 = cvt8(Z0l, Z0h); a1 = cvt8(Z1l, Z1h);
    Z0l = *(const float4*)(pA0 + (c + 5) * 32);
    Z0h = *(const float4*)(pA0 + (c + 5) * 32 + 16);
    Z1l = *(const float4*)(pA1 + (c + 5) * 32);
    Z1h = *(const float4*)(pA1 + (c + 5) * 32 + 16);
    __builtin_amdgcn_sched_barrier(0);
    mfma8(acc, a0, a1, bf);
  }

  loadBf(Bf, 21, g, r16, bf);
  a0 = cvt8(X0l, X0h); a1 = cvt8(X1l, X1h);
  mfma8(acc, a0, a1, bf);
  loadBf(Bf, 22, g, r16, bf);
  a0 = cvt8(Y0l, Y0h); a1 = cvt8(Y1l, Y1h);
  mfma8(acc, a0, a1, bf);
  loadBf(Bf, 23, g, r16, bf);
  a0 = cvt8(Z0l, Z0h); a1 = cvt8(Z1l, Z1h);
  mfma8(acc, a0, a1, bf);

  // tail: 24/25 = name_emb, 26 = type|behav[0:16], 27 = behav[16:32]|0
  const float* pN0 = nemb + (size_t)nm0 * 64 + g * 4;
  const float* pN1 = nemb + (size_t)nm1 * 64 + g * 4;
  #pragma unroll
  for (int t = 0; t < 2; ++t) {
    float4 l0 = *(const float4*)(pN0 + t * 32), h0 = *(const float4*)(pN0 + t * 32 + 16);
    float4 l1 = *(const float4*)(pN1 + t * 32), h1 = *(const float4*)(pN1 + t * 32 + 16);
    loadBf(Bf, 24 + t, g, r16, bf);
    a0 = cvt8(l0, h0); a1 = cvt8(l1, h1);
    mfma8(acc, a0, a1, bf);
  }
  {
    float4 l0 = *(const float4*)(temb + (size_t)tp0 * 16 + g * 4);
    float4 h0 = *(const float4*)(beh + (size_t)arow0 * 32 + g * 4);
    float4 l1 = *(const float4*)(temb + (size_t)tp1 * 16 + g * 4);
    float4 h1 = *(const float4*)(beh + (size_t)arow1 * 32 + g * 4);
    loadBf(Bf, 26, g, r16, bf);
    a0 = cvt8(l0, h0); a1 = cvt8(l1, h1);
    mfma8(acc, a0, a1, bf);
  }
  {
    const float4 z = make_float4(0.f, 0.f, 0.f, 0.f);
    float4 l0 = *(const float4*)(beh + (size_t)arow0 * 32 + 16 + g * 4);
    float4 l1 = *(const float4*)(beh + (size_t)arow1 * 32 + 16 + g * 4);
    loadBf(Bf, 27, g, r16, bf);
    a0 = cvt8(l0, z); a1 = cvt8(l1, z);
    mfma8(acc, a0, a1, bf);
  }

  // epilogue: out(f16) = (acc + biasf) * dinv[node]
  float dv0[4], dv1[4];
  #pragma unroll
  for (int rr = 0; rr < 4; ++rr) {
    int n0 = base + g * 4 + rr;      dv0[rr] = dinv[n0 < n ? n0 : n - 1];
    int n1 = base + 16 + g * 4 + rr; dv1[rr] = dinv[n1 < n ? n1 : n - 1];
  }
  #pragma unroll
  for (int ct = 0; ct < 4; ++ct) {
    int col = ct * 16 + r16;
    float bfc = biasf[col];
    #pragma unroll
    for (int rr = 0; rr < 4; ++rr) {
      int node0 = base + g * 4 + rr;
      if (node0 < n) out[(size_t)node0 * 64 + col] = (_Float16)((acc[0][ct][rr] + bfc) * dv0[rr]);
      int node1 = base + 16 + g * 4 + rr;
      if (node1 < n) out[(size_t)node1 * 64 + col] = (_Float16)((acc[1][ct][rr] + bfc) * dv1[rr]);
    }
  }
}

// ---------------- gemm2: pure f16 (A direct from f16 buffer, no conversion), K=64 ----------------

__global__ __launch_bounds__(256, 4) void gemm2_kernel(
    const _Float16* __restrict__ h, const _Float16* __restrict__ B2f,
    const float* __restrict__ dinv, _Float16* __restrict__ out, int n)
{
  int w = blockIdx.x * 4 + (threadIdx.x >> 6);
  int nw = (n + 31) >> 5;
  if (w >= nw) return;
  int lane = threadIdx.x & 63;
  int g = lane >> 4, r16 = lane & 15;
  int base = w * 32;
  int arow0 = base + r16;      if (arow0 > n - 1) arow0 = n - 1;
  int arow1 = base + 16 + r16; if (arow1 > n - 1) arow1 = n - 1;

  f32x4 acc[2][4];
  #pragma unroll
  for (int i = 0; i < 2; ++i)
    #pragma unroll
    for (int j = 0; j < 4; ++j) { acc[i][j][0] = 0.f; acc[i][j][1] = 0.f; acc[i][j][2] = 0.f; acc[i][j][3] = 0.f; }

  #pragma unroll
  for (int c = 0; c < 2; ++c) {
    f16x8 bf[4];
    loadBf(B2f, c, g, r16, bf);
    const _Float16* p0 = h + (size_t)arow0 * 64 + c * 32 + g * 4;
    const _Float16* p1 = h + (size_t)arow1 * 64 + c * 32 + g * 4;
    f16x4 lo0 = *(const f16x4*)p0, hi0 = *(const f16x4*)(p0 + 16);
    f16x4 lo1 = *(const f16x4*)p1, hi1 = *(const f16x4*)(p1 + 16);
    f16x8 a0, a1;
    a0[0] = lo0[0]; a0[1] = lo0[1]; a0[2] = lo0[2]; a0[3] = lo0[3];
    a0[4] = hi0[0]; a0[5] = hi0[1]; a0[6] = hi0[2]; a0[7] = hi0[3];
    a1[0] = lo1[0]; a1[1] = lo1[1]; a1[2] = lo1[2]; a1[3] = lo1[3];
    a1[4] = hi1[0]; a1[5] = hi1[1]; a1[6] = hi1[2]; a1[7] = hi1[3];
    mfma8(acc, a0, a1, bf);
  }

  float dv0[4], dv1[4];
  #pragma unroll
  for (int rr = 0; rr < 4; ++rr) {
    int n0 = base + g * 4 + rr;      dv0[rr] = dinv[n0 < n ? n0 : n - 1];
    int n1 = base + 16 + g * 4 + rr; dv1[rr] = dinv[n1 < n ? n1 : n - 1];
  }
  #pragma unroll
  for (int ct = 0; ct < 4; ++ct) {
    int col = ct * 16 + r16;
    #pragma unroll
    for (int rr = 0; rr < 4; ++rr) {
      int node0 = base + g * 4 + rr;
      if (node0 < n) out[(size_t)node0 * 64 + col] = (_Float16)(acc[0][ct][rr] * dv0[rr]);
      int node1 = base + 16 + g * 4 + rr;
      if (node1 < n) out[(size_t)node1 * 64 + col] = (_Float16)(acc[1][ct][rr] * dv1[rr]);
    }
  }
}

// ---------------- aggregation: out[j] = relu(bias + dj*(hp[j] + sum ew*hp[src])) ----------------
// hp is f16 dinv-prescaled; gather = 128 B/edge. OUT = _Float16 (feeds gemm2) or float (feeds pool).

template <typename OUT>
__global__ __launch_bounds__(256) void agg_kernel(
    const _Float16* __restrict__ hp, const int* __restrict__ colp,
    const int2* __restrict__ csr, const float* __restrict__ dinv,
    const float* __restrict__ bias, OUT* __restrict__ out, int n)
{
  int wid = threadIdx.x >> 6, lane = threadIdx.x & 63;
  int j = blockIdx.x * 4 + wid;
  if (j >= n) return;
  float dj = dinv[j];
  float hj = (float)hp[(size_t)j * 64 + lane];
  int e0 = colp[j], e1 = colp[j + 1];
  float s0 = 0.0f, s1 = 0.0f;
  int e = e0;
  for (; e + 8 <= e1; e += 8) {
    int2 m0 = csr[e],     m1 = csr[e + 1], m2 = csr[e + 2], m3 = csr[e + 3];
    int2 m4 = csr[e + 4], m5 = csr[e + 5], m6 = csr[e + 6], m7 = csr[e + 7];
    float f0 = (float)hp[(size_t)m0.x * 64 + lane];
    float f1 = (float)hp[(size_t)m1.x * 64 + lane];
    float f2 = (float)hp[(size_t)m2.x * 64 + lane];
    float f3 = (float)hp[(size_t)m3.x * 64 + lane];
    float f4 = (float)hp[(size_t)m4.x * 64 + lane];
    float f5 = (float)hp[(size_t)m5.x * 64 + lane];
    float f6 = (float)hp[(size_t)m6.x * 64 + lane];
    float f7 = (float)hp[(size_t)m7.x * 64 + lane];
    s0 = fmaf(__int_as_float(m0.y), f0, s0);
    s1 = fmaf(__int_as_float(m1.y), f1, s1);
    s0 = fmaf(__int_as_float(m2.y), f2, s0);
    s1 = fmaf(__int_as_float(m3.y), f3, s1);
    s0 = fmaf(__int_as_float(m4.y), f4, s0);
    s1 = fmaf(__int_as_float(m5.y), f5, s1);
    s0 = fmaf(__int_as_float(m6.y), f6, s0);
    s1 = fmaf(__int_as_float(m7.y), f7, s1);
  }
  for (; e + 2 <= e1; e += 2) {
    int2 m0 = csr[e], m1 = csr[e + 1];
    float f0 = (float)hp[(size_t)m0.x * 64 + lane];
    float f1 = (float)hp[(size_t)m1.x * 64 + lane];
    s0 = fmaf(__int_as_float(m0.y), f0, s0);
    s1 = fmaf(__int_as_float(m1.y), f1, s1);
  }
  if (e < e1) {
    int2 m = csr[e];
    s0 = fmaf(__int_as_float(m.y), (float)hp[(size_t)m.x * 64 + lane], s0);
  }
  float acc = bias[lane] + dj * (hj + s0 + s1);
  out[(size_t)j * 64 + lane] = (OUT)fmaxf(acc, 0.0f);
}

// ---------------- pool + classifier ----------------

__global__ __launch_bounds__(256) void pool_kernel(const float* __restrict__ x,
                                                   const int* __restrict__ batch,
                                                   float* __restrict__ pooled, int n) {
  __shared__ float red[4][64];
  __shared__ int range_s[2];
  int gph = blockIdx.x;
  int tid = threadIdx.x, wid = tid >> 6, lane = tid & 63;
  if (tid < 2) {
    int target = gph + tid;
    int lo = 0, hi = n;
    while (lo < hi) { int m = (lo + hi) >> 1; if (batch[m] < target) lo = m + 1; else hi = m; }
    range_s[tid] = lo;
  }
  __syncthreads();
  int lo = range_s[0], hi = range_s[1];
  float acc = 0.0f;
  for (int i = lo + wid; i < hi; i += 4) acc += x[(size_t)i * 64 + lane];
  red[wid][lane] = acc;
  __syncthreads();
  if (tid < 64) {
    float sum = red[0][lane] + red[1][lane] + red[2][lane] + red[3][lane];
    float cntf = (float)(hi - lo);
    pooled[gph * 64 + lane] = sum / fmaxf(cntf, 1.0f);
  }
}

__global__ void cls_kernel(const float* __restrict__ pooled, const float* __restrict__ cw,
                           const float* __restrict__ cb, float* __restrict__ out) {
  int t = threadIdx.x;
  int gph = t >> 1, c = t & 1;
  float acc = cb[c];
  #pragma unroll 8
  for (int k = 0; k < 64; ++k) acc = fmaf(pooled[gph * 64 + k], cw[k * 2 + c], acc);
  out[gph * 2 + c] = acc;
}

// ---------------- launch ----------------

extern "C" void kernel_launch(void* const* d_in, const int* in_sizes, int n_in,
                              void* d_out, int out_size, void* d_ws, size_t ws_size,
                              hipStream_t stream) {
  const int*   x_names  = (const int*)  d_in[0];
  const int*   x_types  = (const int*)  d_in[1];
  const float* behav    = (const float*)d_in[2];
  const int*   ei       = (const int*)  d_in[3];
  const float* ew       = (const float*)d_in[4];
  const int*   batch    = (const int*)  d_in[5];
  const float* llm      = (const float*)d_in[6];
  const float* name_emb = (const float*)d_in[7];
  const float* type_emb = (const float*)d_in[8];
  const float* pw       = (const float*)d_in[9];
  const float* pb       = (const float*)d_in[10];
  const float* w1       = (const float*)d_in[11];
  const float* b1       = (const float*)d_in[12];
  const float* w2       = (const float*)d_in[13];
  const float* b2       = (const float*)d_in[14];
  const float* cw       = (const float*)d_in[15];
  const float* cb       = (const float*)d_in[16];

  const int N = in_sizes[0];
  const int E = in_sizes[4];
  const int nb = (N + 255) / 256;
  const int eb = (E + 255) / 256;
  const int gblocks = ((N + 31) / 32 + 3) / 4;

  char* p = (char*)d_ws;
  auto alloc = [&](size_t bytes) -> void* {
    void* r = (void*)p; p += (bytes + 255) & ~(size_t)255; return r;
  };
  float*     dinv   = (float*)    alloc((size_t)N * 4);
  int*       cnt    = (int*)      alloc((size_t)N * 4);
  int*       colp   = (int*)      alloc((size_t)(N + 1) * 4);
  int*       fillp  = (int*)      alloc((size_t)N * 4);
  int2*      csr    = (int2*)     alloc((size_t)E * 8);
  int*       bsum   = (int*)      alloc((size_t)(nb + 1) * 4);
  _Float16*  Bf     = (_Float16*) alloc((size_t)896 * 64 * 2);
  _Float16*  B2f    = (_Float16*) alloc((size_t)64 * 64 * 2);
  float*     biasf  = (float*)    alloc((size_t)64 * 4);
  _Float16*  hp1    = (_Float16*) alloc((size_t)N * 64 * 2);
  _Float16*  y1     = (_Float16*) alloc((size_t)N * 64 * 2);
  _Float16*  hp2    = (_Float16*) alloc((size_t)N * 64 * 2);
  float*     y2     = (float*)    alloc((size_t)N * 64 * 4);
  float*     pooled = (float*)    alloc((size_t)128 * 64 * 4);
  (void)ws_size; (void)n_in; (void)out_size;

  prep_kernel<<<(896 * 64 + 64 + 64 * 64 + 255) / 256, 256, 0, stream>>>(
      pw, pb, w1, w2, Bf, biasf, B2f);
  hipMemsetAsync(cnt, 0, (size_t)N * 4, stream);
  cnt_kernel<<<eb, 256, 0, stream>>>(ei, cnt, E);
  scan_blk<<<nb, 256, 0, stream>>>(cnt, colp, bsum, N);
  scan_top<<<1, 512, 0, stream>>>(bsum, colp, nb, N);
  scan_add<<<nb, 256, 0, stream>>>(colp, fillp, bsum, N);
  fill_kernel<<<eb, 256, 0, stream>>>(ei, ew, fillp, csr, E);
  degsum_kernel<<<nb, 256, 0, stream>>>(colp, csr, dinv, N);

  gemm1_kernel<<<gblocks, 256, 0, stream>>>(llm, Bf, x_names, x_types, behav,
                                            name_emb, type_emb, biasf, dinv, hp1, N);
  agg_kernel<_Float16><<<(N + 3) / 4, 256, 0, stream>>>(hp1, colp, csr, dinv, b1, y1, N);
  gemm2_kernel<<<gblocks, 256, 0, stream>>>(y1, B2f, dinv, hp2, N);
  agg_kernel<float><<<(N + 3) / 4, 256, 0, stream>>>(hp2, colp, csr, dinv, b2, y2, N);
  pool_kernel<<<128, 256, 0, stream>>>(y2, batch, pooled, N);
  cls_kernel<<<1, 256, 0, stream>>>(pooled, cw, cb, (float*)d_out);
}